// Round 1
// 203.420 us; speedup vs baseline: 1.0458x; 1.0458x over previous
//
#include <hip/hip_runtime.h>
#include <hip/hip_bf16.h>

typedef __attribute__((ext_vector_type(8))) short short8;
typedef __attribute__((ext_vector_type(4))) short short4_t;
typedef __attribute__((ext_vector_type(4))) float float4_t;
typedef unsigned short ushort;

#define HW 4096
#define CC 256
#define NBATCH 4
#define SEQ ((size_t)NBATCH * HW)

static __device__ __forceinline__ unsigned short f2b(float f) {
    union { float f; unsigned u; } v; v.f = f;
    unsigned r = v.u + 0x7FFF + ((v.u >> 16) & 1);   // RNE
    return (unsigned short)(r >> 16);
}
static __device__ __forceinline__ float b2f(unsigned short u) {
    union { unsigned u; float f; } v; v.u = ((unsigned)u) << 16;
    return v.f;
}
// packed RNE f32x2 -> bf16x2 (v_cvt_pk_bf16_f32 on gfx950)
static __device__ __forceinline__ unsigned pk2(float a, float b) {
    __hip_bfloat162 h = __float22bfloat162_rn(make_float2(a, b));
    union { __hip_bfloat162 h; unsigned u; } v; v.h = h; return v.u;
}

// r16: barrier that makes cross-wave LDS traffic visible WITHOUT draining
// vmcnt — outstanding global prefetches (kregs/vregs -> private VGPRs) stay
// in flight across the barrier; the compiler inserts the vmcnt wait at their
// consumption point (ds_write / MFMA) one full phase later. T4-minimal.
static __device__ __forceinline__ void barrier_lds() {
    asm volatile("s_waitcnt lgkmcnt(0)" ::: "memory");
    __builtin_amdgcn_s_barrier();
    __builtin_amdgcn_sched_barrier(0);
}

// ---- kernel 1: x[n][c][p] -> XT[n][p][c] (bf16) and gb[n][c][p] (bf16),
//      with fused fp32->bf16 weight conversion (first 768 flat blocks). ----
__global__ __launch_bounds__(256) void k_prep(const float* __restrict__ x,
                                              const float* __restrict__ tw,
                                              const float* __restrict__ pw,
                                              const float* __restrict__ cw,
                                              unsigned short* __restrict__ XT,
                                              unsigned short* __restrict__ gb,
                                              unsigned short* __restrict__ Wbt,
                                              unsigned short* __restrict__ Wbp,
                                              unsigned short* __restrict__ Wbc) {
    __shared__ float T[64][65];
    int fb = blockIdx.x + 64 * (blockIdx.y + 4 * blockIdx.z);
    if (fb < 768) {            // 768*256 = 196608 = 3 x 256x256 weights
        int i = fb * 256 + threadIdx.x;
        int sel = i >> 16, off = i & 65535;
        const float* s = sel == 0 ? tw : (sel == 1 ? pw : cw);
        unsigned short* d = sel == 0 ? Wbt : (sel == 1 ? Wbp : Wbc);
        d[off] = f2b(s[off]);
    }
    int n = blockIdx.z, c0 = blockIdx.y * 64, p0 = blockIdx.x * 64;
    int t = threadIdx.x;
    int pl = t & 63, rg = t >> 6;
    const float* xp = x + ((size_t)n * CC + c0) * HW + p0;
    #pragma unroll
    for (int i = 0; i < 16; i++) {
        int cl = rg * 16 + i;
        float v = xp[(size_t)cl * HW + pl];
        T[cl][pl] = v;
        gb[((size_t)n * CC + c0 + cl) * HW + p0 + pl] = f2b(v);
    }
    __syncthreads();
    int cl = t & 63, pg = t >> 6;
    unsigned short* xt = XT + ((size_t)n * HW + p0) * CC + c0;
    #pragma unroll
    for (int i = 0; i < 16; i++) {
        int plw = pg * 16 + i;
        xt[(size_t)plw * CC + cl] = f2b(T[cl][plw]);
    }
}

// ---- kernel 2: projection GEMM  outT[p][co] = sum_ci XT[p][ci]*W[co][ci] + b[co] ----
__global__ __launch_bounds__(256) void k_proj(const unsigned short* __restrict__ XT,
                                              const unsigned short* __restrict__ Wt,
                                              const unsigned short* __restrict__ Wp,
                                              const float* __restrict__ bt,
                                              const float* __restrict__ bp,
                                              unsigned short* __restrict__ outT_t,
                                              unsigned short* __restrict__ outT_p) {
    const unsigned short* W; const float* b; unsigned short* outT;
    if (blockIdx.y == 0) { W = Wt; b = bt; outT = outT_t; }
    else                 { W = Wp; b = bp; outT = outT_p; }
    int w = threadIdx.x >> 6, lane = threadIdx.x & 63;
    int nidx = lane & 15, quad = lane >> 4;
    size_t row0 = (size_t)blockIdx.x * 64 + w * 16;
    float4_t acc[16];
    #pragma unroll
    for (int i = 0; i < 16; i++) acc[i] = (float4_t)(0.f);
    const unsigned short* arow = XT + (row0 + nidx) * CC + quad * 8;
    for (int ks = 0; ks < 8; ks++) {
        short8 a = *(const short8*)(arow + ks * 32);
        #pragma unroll
        for (int cb = 0; cb < 16; cb++) {
            short8 bb = *(const short8*)(W + (size_t)(cb * 16 + nidx) * CC + ks * 32 + quad * 8);
            acc[cb] = __builtin_amdgcn_mfma_f32_16x16x32_bf16(a, bb, acc[cb], 0, 0, 0);
        }
    }
    #pragma unroll
    for (int cb = 0; cb < 16; cb++) {
        int co = cb * 16 + nidx;
        float bias = b[co];
        #pragma unroll
        for (int r = 0; r < 4; r++) {
            size_t prow = row0 + quad * 4 + r;
            outT[prow * CC + co] = f2b(acc[cb][r] + bias);
        }
    }
}

// ---- kernel 3 (round-16): r15 structure + (a) lgkmcnt-only barriers so the
// per-ITER global prefetches (loadKregs t+3 / loadVregs t+1) are no longer
// drained by __syncthreads' vmcnt(0) at every one of the 32 iterations (T4
// minimal form), and (b) s_setprio(1) around the QK+PV MFMA cluster (T5,
// +4-7% on attn per m191). Dataflow/barrier count unchanged from r15.
__global__ __launch_bounds__(512)
void k_attn(const unsigned short* __restrict__ thetaT,
            const unsigned short* __restrict__ phiT,
            const unsigned short* __restrict__ gb,
            ushort* __restrict__ Ow, float* __restrict__ lw) {
    __shared__ __align__(16) ushort Kl[2][16384];        // frag-major, 64 KB
    __shared__ __align__(16) ushort Pbuf[2][16][64][8];  // frag-major, 32 KB
    __shared__ float Lbuf[2][128];

    const int tid = threadIdx.x;
    const int w = tid >> 6, lane = tid & 63;
    const int nidx = lane & 15, quad = lane >> 4;
    const int qg = w & 3;                                // q-group (32 q) for QK
    const int kh = w >> 2;                               // key-half (32 keys) for QK
    const int nb = (blockIdx.x & 7) >> 1;                // batch -> XCD pair
    const int h  = blockIdx.x & 1;                       // key half (kernel-level split)
    const int qtile = blockIdx.x >> 3;                   // 0..31
    const int p0 = qtile * 128;
    const size_t seq0 = (size_t)nb * HW;
    const ushort* Kg = phiT + seq0 * CC;                 // [4096][256]
    const ushort* Vg = gb + (size_t)nb * CC * HW;        // [256][4096]
    const int k00 = h * 2048;

    // persistent theta frags (B operand, n=q): wave's 32 queries
    short8 th[2][8];
    #pragma unroll
    for (int qs = 0; qs < 2; qs++) {
        const ushort* qrow = thetaT + (seq0 + p0 + qg * 32 + qs * 16 + nidx) * CC + quad * 8;
        #pragma unroll
        for (int kb = 0; kb < 8; kb++) th[qs][kb] = *(const short8*)(qrow + kb * 32);
    }

    float4_t o[2][8];                                    // ch=w*32+mg*16+quad*4+r, q=qq*16+nidx
    #pragma unroll
    for (int i = 0; i < 2; i++)
        #pragma unroll
        for (int j = 0; j < 8; j++) o[i][j] = (float4_t)(0.f);
    float lrow[2] = {0.f, 0.f};                          // q = qg*32 + qs*16 + nidx

    // K staging (conflict-free): thread -> key n_s = tid&15, chunk c_s = tid>>4
    const int c_s = tid >> 4, n_s = tid & 15;
    const int kfbase = (c_s >> 2) * 512 + ((c_s & 3) * 16 + n_s) * 8;
    auto loadKregs = [&](short8 (&kr)[4], int tt) {
        #pragma unroll
        for (int rr = 0; rr < 4; rr++)
            kr[rr] = *(const short8*)(Kg + (size_t)(k00 + tt * 64 + rr * 16 + n_s) * CC + c_s * 8);
    };
    auto stageK = [&](int buf, const short8 (&kr)[4]) {
        #pragma unroll
        for (int rr = 0; rr < 4; rr++) *(short8*)(&Kl[buf][rr * 4096 + kfbase]) = kr[rr];
    };
    auto loadVregs = [&](short8 (&vr)[4], int tt) {
        #pragma unroll
        for (int mg = 0; mg < 2; mg++)
            #pragma unroll
            for (int kst = 0; kst < 2; kst++)
                vr[mg * 2 + kst] = *(const short8*)(Vg + (size_t)(w * 32 + mg * 16 + nidx) * HW
                                                    + k00 + tt * 64 + kst * 32 + quad * 8);
    };

    const float SC = 0.0625f * 1.44269504088896f;        // /sqrt(256) * log2(e)
    // P-write cells (swapped QK): acc s[kgrp][qs] holds keys kgrp*16+quad*4+r
    // at q=nidx. Octet G = quad>>1; cell = (kgrp*2+G)*16 + (nidx ^ (G*4));
    // elem j0 = (quad&1)*4. XOR-4 swizzle spreads even/odd-quad banks.
    const int Gp = quad >> 1;
    const int pcell_lo = (nidx ^ (Gp * 4));              // low cell index part
    const int pj0 = (quad & 1) * 4;
    // P-read cell for consumer lane: octet = lane>>4, q = lane&15, same XOR
    const int prcell = ((lane >> 4) << 4) | ((lane & 15) ^ (((lane >> 4) & 1) * 4));

    float4_t s00, s01, s10, s11;                         // s[kgrp][qs]
    auto expPhase = [&](int buf) {
        {
            float e0 = exp2f(s00[0] * SC), e1 = exp2f(s00[1] * SC);
            float e2 = exp2f(s00[2] * SC), e3 = exp2f(s00[3] * SC);
            lrow[0] += (e0 + e1) + (e2 + e3);
            uint2 pk; pk.x = pk2(e0, e1); pk.y = pk2(e2, e3);
            *(uint2*)(&Pbuf[buf][(qg * 2 + 0) * 2 + kh][(0 * 2 + Gp) * 16 + pcell_lo][pj0]) = pk;
        }
        {
            float e0 = exp2f(s01[0] * SC), e1 = exp2f(s01[1] * SC);
            float e2 = exp2f(s01[2] * SC), e3 = exp2f(s01[3] * SC);
            lrow[1] += (e0 + e1) + (e2 + e3);
            uint2 pk; pk.x = pk2(e0, e1); pk.y = pk2(e2, e3);
            *(uint2*)(&Pbuf[buf][(qg * 2 + 1) * 2 + kh][(0 * 2 + Gp) * 16 + pcell_lo][pj0]) = pk;
        }
        {
            float e0 = exp2f(s10[0] * SC), e1 = exp2f(s10[1] * SC);
            float e2 = exp2f(s10[2] * SC), e3 = exp2f(s10[3] * SC);
            lrow[0] += (e0 + e1) + (e2 + e3);
            uint2 pk; pk.x = pk2(e0, e1); pk.y = pk2(e2, e3);
            *(uint2*)(&Pbuf[buf][(qg * 2 + 0) * 2 + kh][(1 * 2 + Gp) * 16 + pcell_lo][pj0]) = pk;
        }
        {
            float e0 = exp2f(s11[0] * SC), e1 = exp2f(s11[1] * SC);
            float e2 = exp2f(s11[2] * SC), e3 = exp2f(s11[3] * SC);
            lrow[1] += (e0 + e1) + (e2 + e3);
            uint2 pk; pk.x = pk2(e0, e1); pk.y = pk2(e2, e3);
            *(uint2*)(&Pbuf[buf][(qg * 2 + 1) * 2 + kh][(1 * 2 + Gp) * 16 + pcell_lo][pj0]) = pk;
        }
    };

    short8 kregs[4], vA[4], vB[4];

    // merged iteration t: PV(t)+QK(t+1) -> loads (r11/r13 placement) -> exp -> barrier
    auto ITER = [&](int t, const short8 (&vCur)[4], short8 (&vNext)[4]) {
        const int pb = t & 1;                            // P buffer for PV(t)
        const int kbuf = (t + 1) & 1;                    // Kl buffer for QK(t+1)
        s00 = (float4_t)(0.f); s01 = (float4_t)(0.f);
        s10 = (float4_t)(0.f); s11 = (float4_t)(0.f);
        __builtin_amdgcn_s_setprio(1);
        #pragma unroll
        for (int i = 0; i < 8; i++) {
            short8 k0 = *(const short8*)(&Kl[kbuf][((kh * 2 + 0) * 8 + i) * 512 + lane * 8]);
            short8 k1 = *(const short8*)(&Kl[kbuf][((kh * 2 + 1) * 8 + i) * 512 + lane * 8]);
            // A = K (m=key), B = theta (n=q)
            s00 = __builtin_amdgcn_mfma_f32_16x16x32_bf16(k0, th[0][i], s00, 0, 0, 0);
            s01 = __builtin_amdgcn_mfma_f32_16x16x32_bf16(k0, th[1][i], s01, 0, 0, 0);
            s10 = __builtin_amdgcn_mfma_f32_16x16x32_bf16(k1, th[0][i], s10, 0, 0, 0);
            s11 = __builtin_amdgcn_mfma_f32_16x16x32_bf16(k1, th[1][i], s11, 0, 0, 0);
            short8 pf0 = *(const short8*)(&Pbuf[pb][i * 2 + 0][prcell][0]);
            short8 pf1 = *(const short8*)(&Pbuf[pb][i * 2 + 1][prcell][0]);
            o[0][i] = __builtin_amdgcn_mfma_f32_16x16x32_bf16(vCur[0], pf0, o[0][i], 0, 0, 0);
            o[0][i] = __builtin_amdgcn_mfma_f32_16x16x32_bf16(vCur[1], pf1, o[0][i], 0, 0, 0);
            o[1][i] = __builtin_amdgcn_mfma_f32_16x16x32_bf16(vCur[2], pf0, o[1][i], 0, 0, 0);
            o[1][i] = __builtin_amdgcn_mfma_f32_16x16x32_bf16(vCur[3], pf1, o[1][i], 0, 0, 0);
        }
        __builtin_amdgcn_s_setprio(0);
        loadVregs(vNext, t + 1);                          // WAR-safe: PV(t) consumed vCur
        expPhase((t + 1) & 1);
        if (t < 30) {
            stageK((t + 2) & 1, kregs);                   // Kl[t&1] safe per barrier(t-1)
            loadKregs(kregs, (t + 3 < 32) ? t + 3 : 31);
        }
        barrier_lds();                                    // P(t+1) + Kl[t+2] ready; vmcnt free-running
    };

    // ---- prologue ----
    loadKregs(kregs, 0); loadVregs(vA, 0);
    stageK(0, kregs);
    loadKregs(kregs, 1);
    barrier_lds();                                       // Kl[0] ready
    s00 = (float4_t)(0.f); s01 = (float4_t)(0.f); s10 = (float4_t)(0.f); s11 = (float4_t)(0.f);
    __builtin_amdgcn_s_setprio(1);
    #pragma unroll
    for (int kb = 0; kb < 8; kb++) {
        short8 k0 = *(const short8*)(&Kl[0][((kh * 2 + 0) * 8 + kb) * 512 + lane * 8]);
        short8 k1 = *(const short8*)(&Kl[0][((kh * 2 + 1) * 8 + kb) * 512 + lane * 8]);
        s00 = __builtin_amdgcn_mfma_f32_16x16x32_bf16(k0, th[0][kb], s00, 0, 0, 0);
        s01 = __builtin_amdgcn_mfma_f32_16x16x32_bf16(k0, th[1][kb], s01, 0, 0, 0);
        s10 = __builtin_amdgcn_mfma_f32_16x16x32_bf16(k1, th[0][kb], s10, 0, 0, 0);
        s11 = __builtin_amdgcn_mfma_f32_16x16x32_bf16(k1, th[1][kb], s11, 0, 0, 0);
    }
    __builtin_amdgcn_s_setprio(0);
    expPhase(0);
    stageK(1, kregs);                                    // Kl[1] = K(1)
    loadKregs(kregs, 2);
    barrier_lds();                                       // P(0) + Kl[1] ready

    // ---- main loop: 31 merged iters (even/odd static V buffers) ----
    #pragma unroll 1
    for (int tt = 0; tt < 15; tt++) {
        ITER(tt * 2, vA, vB);
        ITER(tt * 2 + 1, vB, vA);
    }
    ITER(30, vA, vB);
    // ---- final PV(31): Pbuf[1], vB = V(31) ----
    #pragma unroll
    for (int i = 0; i < 8; i++) {
        short8 pf0 = *(const short8*)(&Pbuf[1][i * 2 + 0][prcell][0]);
        short8 pf1 = *(const short8*)(&Pbuf[1][i * 2 + 1][prcell][0]);
        o[0][i] = __builtin_amdgcn_mfma_f32_16x16x32_bf16(vB[0], pf0, o[0][i], 0, 0, 0);
        o[0][i] = __builtin_amdgcn_mfma_f32_16x16x32_bf16(vB[1], pf1, o[0][i], 0, 0, 0);
        o[1][i] = __builtin_amdgcn_mfma_f32_16x16x32_bf16(vB[2], pf0, o[1][i], 0, 0, 0);
        o[1][i] = __builtin_amdgcn_mfma_f32_16x16x32_bf16(vB[3], pf1, o[1][i], 0, 0, 0);
    }

    // ---- epilogue: l (lane q=nidx; reduce over quads, then kh waves) ----
    #pragma unroll
    for (int qs = 0; qs < 2; qs++) {
        float v = lrow[qs];
        v += __shfl_xor(v, 16);
        v += __shfl_xor(v, 32);
        if (quad == 0) Lbuf[kh][qg * 32 + qs * 16 + nidx] = v;
    }
    __syncthreads();
    if (tid < 128)
        lw[(size_t)h * SEQ + seq0 + p0 + tid] = Lbuf[0][tid] + Lbuf[1][tid];
    ushort* Op = Ow + ((size_t)h * SEQ + seq0 + p0) * CC;
    #pragma unroll
    for (int mg = 0; mg < 2; mg++)
        #pragma unroll
        for (int qq = 0; qq < 8; qq++) {
            uint2 pk;
            pk.x = pk2(o[mg][qq][0], o[mg][qq][1]);
            pk.y = pk2(o[mg][qq][2], o[mg][qq][3]);
            *(uint2*)(Op + (size_t)(qq * 16 + nidx) * CC + w * 32 + mg * 16 + quad * 4) = pk;
        }
}

// ---- kernel 4 (round-16): fused reduce+final. One block per (p-tile, n):
// combine the two key-half partials once into a swizzled LDS tile (was
// k_reduce's HBM round-trip + 4x redundant fT fetch), then MFMA from LDS.
// out[n][co][p] = x + b[co] + sum_k W[co][k] * fT[p][k]
__global__ __launch_bounds__(512)
void k_final(const unsigned short* __restrict__ Wc,
             const float* __restrict__ bc,
             const ushort* __restrict__ Ow,
             const float* __restrict__ lw,
             const float* __restrict__ x,
             float* __restrict__ out) {
    __shared__ __align__(16) ushort F[64][256];          // combined fT tile, XOR-swizzled
    const int n = blockIdx.z;
    const int p0 = blockIdx.x * 64;
    const int tid = threadIdx.x;

    // stage+combine: thread -> row r = tid>>3, chunks (tid&7)+8i (16B each)
    {
        const int r = tid >> 3;
        const int c0 = tid & 7;
        const size_t grow = (size_t)n * HW + p0 + r;
        const float li = 1.0f / (lw[grow] + lw[SEQ + grow]);
        const short8* O0 = (const short8*)(Ow + grow * CC);
        const short8* O1 = (const short8*)(Ow + SEQ * CC + grow * CC);
        #pragma unroll
        for (int i = 0; i < 4; i++) {
            int ch = c0 + 8 * i;
            short8 a = O0[ch];
            short8 b = O1[ch];
            union { short8 s; unsigned u[4]; } pk;
            float f[8];
            #pragma unroll
            for (int j = 0; j < 8; j++)
                f[j] = (b2f((ushort)a[j]) + b2f((ushort)b[j])) * li;
            pk.u[0] = pk2(f[0], f[1]); pk.u[1] = pk2(f[2], f[3]);
            pk.u[2] = pk2(f[4], f[5]); pk.u[3] = pk2(f[6], f[7]);
            int swz = ch ^ (r & 7);                      // bank-spread (G4)
            *(short8*)(&F[r][swz * 8]) = pk.s;
        }
    }
    __syncthreads();

    const int w = tid >> 6, lane = tid & 63;
    const int nidx = lane & 15, quad = lane >> 4;
    const int co_base = w * 32;
    float4_t acc[2][4];
    #pragma unroll
    for (int i = 0; i < 2; i++)
        #pragma unroll
        for (int j = 0; j < 4; j++) acc[i][j] = (float4_t)(0.f);

    const unsigned short* a0row = Wc + (size_t)(co_base + nidx) * CC + quad * 8;
    const unsigned short* a1row = Wc + (size_t)(co_base + 16 + nidx) * CC + quad * 8;
    for (int ks = 0; ks < 8; ks++) {
        short8 a0 = *(const short8*)(a0row + ks * 32);
        short8 a1 = *(const short8*)(a1row + ks * 32);
        #pragma unroll
        for (int pb = 0; pb < 4; pb++) {
            int row = pb * 16 + nidx;
            int chunk = (ks * 4 + quad) ^ (row & 7);     // matches write swizzle
            short8 bb = *(const short8*)(&F[row][chunk * 8]);
            acc[0][pb] = __builtin_amdgcn_mfma_f32_16x16x32_bf16(a0, bb, acc[0][pb], 0, 0, 0);
            acc[1][pb] = __builtin_amdgcn_mfma_f32_16x16x32_bf16(a1, bb, acc[1][pb], 0, 0, 0);
        }
    }

    #pragma unroll
    for (int cb = 0; cb < 2; cb++) {
        #pragma unroll
        for (int pb = 0; pb < 4; pb++) {
            #pragma unroll
            for (int r2 = 0; r2 < 4; r2++) {
                int co = co_base + cb * 16 + quad * 4 + r2;
                size_t idx = ((size_t)n * CC + co) * HW + p0 + pb * 16 + nidx;
                out[idx] = x[idx] + bc[co] + acc[cb][pb][r2];
            }
        }
    }
}

extern "C" void kernel_launch(void* const* d_in, const int* in_sizes, int n_in,
                              void* d_out, int out_size, void* d_ws, size_t ws_size,
                              hipStream_t stream) {
    const float* x       = (const float*)d_in[0];
    const float* theta_w = (const float*)d_in[1];
    const float* theta_b = (const float*)d_in[2];
    const float* phi_w   = (const float*)d_in[3];
    const float* phi_b   = (const float*)d_in[4];
    const float* conv1_w = (const float*)d_in[5];
    const float* conv1_b = (const float*)d_in[6];
    float* out = (float*)d_out;

    unsigned short* XT  = (unsigned short*)d_ws;  // [SEQ][256] bf16
    unsigned short* gb  = XT  + SEQ * CC;         // [N][256][4096]
    unsigned short* thT = gb  + SEQ * CC;         // [SEQ][256]
    unsigned short* phT = thT + SEQ * CC;         // [SEQ][256]
    unsigned short* fT  = phT + SEQ * CC;         // [SEQ][256] (unused since r16 fusion)
    unsigned short* Wbt = fT  + SEQ * CC;
    unsigned short* Wbp = Wbt + 65536;
    unsigned short* Wbc = Wbp + 65536;
    unsigned short* Ow  = Wbc + 65536;            // [2][SEQ][256] bf16 partial O
    float* lw = (float*)(Ow + 2 * SEQ * CC);      // [2][SEQ] fp32 partial l

    k_prep<<<dim3(64, 4, 4), 256, 0, stream>>>(x, theta_w, phi_w, conv1_w, XT, gb, Wbt, Wbp, Wbc);
    k_proj<<<dim3(256, 2), 256, 0, stream>>>(XT, Wbt, Wbp, theta_b, phi_b, thT, phT);
    k_attn<<<dim3(256), 512, 0, stream>>>(thT, phT, gb, Ow, lw);
    k_final<<<dim3(64, 1, 4), 512, 0, stream>>>(Wbc, conv1_b, Ow, lw, x, out);
}

// Round 3
// 183.820 us; speedup vs baseline: 1.1574x; 1.1066x over previous
//
#include <hip/hip_runtime.h>
#include <hip/hip_bf16.h>

typedef __attribute__((ext_vector_type(8))) short short8;
typedef __attribute__((ext_vector_type(4))) short short4_t;
typedef __attribute__((ext_vector_type(4))) float float4_t;
typedef unsigned short ushort;

#define HW 4096
#define CC 256
#define NBATCH 4
#define SEQ ((size_t)NBATCH * HW)

static __device__ __forceinline__ unsigned short f2b(float f) {
    union { float f; unsigned u; } v; v.f = f;
    unsigned r = v.u + 0x7FFF + ((v.u >> 16) & 1);   // RNE
    return (unsigned short)(r >> 16);
}
static __device__ __forceinline__ float b2f(unsigned short u) {
    union { unsigned u; float f; } v; v.u = ((unsigned)u) << 16;
    return v.f;
}
// packed RNE f32x2 -> bf16x2 (v_cvt_pk_bf16_f32 on gfx950)
static __device__ __forceinline__ unsigned pk2(float a, float b) {
    __hip_bfloat162 h = __float22bfloat162_rn(make_float2(a, b));
    union { __hip_bfloat162 h; unsigned u; } v; v.h = h; return v.u;
}

// ---- kernel 1 (round-17/18): fused prep+proj. One block per (p-tile=64, n).
// Phase A: stage x[n][:, p0..p0+63] through fp32 LDS transpose into an
// XOR-swizzled bf16 tile F[p][c] (writing gb bf16 on the way through).
// Phase B: theta & phi projections from F (waves 0-3 theta, 4-7 phi,
// 64 output channels each; fp32 weights converted in-register via cvt_pk).
// Replaces k_prep + k_proj: deletes one launch + XT write/2x-read and the
// Wb* preconversion. Numerically identical (same RNE everywhere).
__global__ __launch_bounds__(512)
void k_pp(const float* __restrict__ x,
          const float* __restrict__ tw, const float* __restrict__ pw,
          const float* __restrict__ thb, const float* __restrict__ phb,
          unsigned short* __restrict__ gb,
          unsigned short* __restrict__ thT, unsigned short* __restrict__ phT) {
    __shared__ float T[64][65];
    __shared__ __align__(16) ushort F[64][256];          // [p][c], chunk-XOR swizzled
    const int n = blockIdx.z;
    const int p0 = blockIdx.x * 64;
    const int tid = threadIdx.x;

    // ---- Phase A: 4 chunks of 64 channels ----
    {
        const int pl = tid & 63, rg = tid >> 6;          // loader: 8 row-groups x 8 rows
        for (int cc = 0; cc < 4; cc++) {
            const int c0 = cc * 64;
            const float* xp = x + ((size_t)n * CC + c0) * HW + p0;
            #pragma unroll
            for (int i = 0; i < 8; i++) {
                int cl = rg * 8 + i;
                float v = xp[(size_t)cl * HW + pl];
                T[cl][pl] = v;
                gb[((size_t)n * CC + c0 + cl) * HW + p0 + pl] = f2b(v);
            }
            __syncthreads();
            // transposed read (pitch 65 -> conflict-free), swizzled bf16 write
            const int cl2 = tid & 63, pg = tid >> 6;
            #pragma unroll
            for (int i = 0; i < 8; i++) {
                int plw = pg * 8 + i;
                int c = c0 + cl2;
                int swz = (c >> 3) ^ (plw & 7);          // 16B-chunk XOR swizzle (G4)
                F[plw][swz * 8 + (c & 7)] = f2b(T[cl2][plw]);
            }
            __syncthreads();                             // T reusable / F chunk done
        }
    }

    // ---- Phase B: projections. A = F rows (m=p), B = W rows (n=co). ----
    const int w = tid >> 6, lane = tid & 63;
    const int nidx = lane & 15, quad = lane >> 4;
    const float* Wsel = (w < 4) ? tw : pw;
    const float* bsel = (w < 4) ? thb : phb;
    unsigned short* osel = (w < 4) ? thT : phT;
    const int cq = w & 3;                                // 64-col slice per wave

    float4_t acc[4][4];                                  // [mt (p)][cb (co)]
    #pragma unroll
    for (int i = 0; i < 4; i++)
        #pragma unroll
        for (int j = 0; j < 4; j++) acc[i][j] = (float4_t)(0.f);

    for (int ks = 0; ks < 8; ks++) {
        short8 af[4];
        #pragma unroll
        for (int mt = 0; mt < 4; mt++) {
            int row = mt * 16 + nidx;
            int chn = (ks * 4 + quad) ^ (row & 7);       // matches write swizzle
            af[mt] = *(const short8*)(&F[row][chn * 8]);
        }
        #pragma unroll
        for (int cb = 0; cb < 4; cb++) {
            int co = cq * 64 + cb * 16 + nidx;
            const float* wp = Wsel + (size_t)co * CC + ks * 32 + quad * 8;
            float4_t w0 = *(const float4_t*)(wp);
            float4_t w1 = *(const float4_t*)(wp + 4);
            union { short8 s; unsigned u[4]; } bfr;
            bfr.u[0] = pk2(w0[0], w0[1]); bfr.u[1] = pk2(w0[2], w0[3]);
            bfr.u[2] = pk2(w1[0], w1[1]); bfr.u[3] = pk2(w1[2], w1[3]);
            #pragma unroll
            for (int mt = 0; mt < 4; mt++)
                acc[mt][cb] = __builtin_amdgcn_mfma_f32_16x16x32_bf16(af[mt], bfr.s, acc[mt][cb], 0, 0, 0);
        }
    }

    #pragma unroll
    for (int cb = 0; cb < 4; cb++) {
        int co = cq * 64 + cb * 16 + nidx;
        float bias = bsel[co];
        #pragma unroll
        for (int mt = 0; mt < 4; mt++)
            #pragma unroll
            for (int r = 0; r < 4; r++) {
                size_t prow = (size_t)n * HW + p0 + mt * 16 + quad * 4 + r;
                osel[prow * CC + co] = f2b(acc[mt][cb][r] + bias);
            }
    }
}

// ---- kernel 3: exact r15 body — plain __syncthreads, no setprio (r16's
// hand barriers + setprio regressed 84.2 -> 91.0 us in this lockstep
// 8-wave structure). Best measured: 84.2 us. ----
__global__ __launch_bounds__(512)
void k_attn(const unsigned short* __restrict__ thetaT,
            const unsigned short* __restrict__ phiT,
            const unsigned short* __restrict__ gb,
            ushort* __restrict__ Ow, float* __restrict__ lw) {
    __shared__ __align__(16) ushort Kl[2][16384];        // frag-major, 64 KB
    __shared__ __align__(16) ushort Pbuf[2][16][64][8];  // frag-major, 32 KB
    __shared__ float Lbuf[2][128];

    const int tid = threadIdx.x;
    const int w = tid >> 6, lane = tid & 63;
    const int nidx = lane & 15, quad = lane >> 4;
    const int qg = w & 3;                                // q-group (32 q) for QK
    const int kh = w >> 2;                               // key-half (32 keys) for QK
    const int nb = (blockIdx.x & 7) >> 1;                // batch -> XCD pair
    const int h  = blockIdx.x & 1;                       // key half (kernel-level split)
    const int qtile = blockIdx.x >> 3;                   // 0..31
    const int p0 = qtile * 128;
    const size_t seq0 = (size_t)nb * HW;
    const ushort* Kg = phiT + seq0 * CC;                 // [4096][256]
    const ushort* Vg = gb + (size_t)nb * CC * HW;        // [256][4096]
    const int k00 = h * 2048;

    // persistent theta frags (B operand, n=q): wave's 32 queries
    short8 th[2][8];
    #pragma unroll
    for (int qs = 0; qs < 2; qs++) {
        const ushort* qrow = thetaT + (seq0 + p0 + qg * 32 + qs * 16 + nidx) * CC + quad * 8;
        #pragma unroll
        for (int kb = 0; kb < 8; kb++) th[qs][kb] = *(const short8*)(qrow + kb * 32);
    }

    float4_t o[2][8];                                    // ch=w*32+mg*16+quad*4+r, q=qq*16+nidx
    #pragma unroll
    for (int i = 0; i < 2; i++)
        #pragma unroll
        for (int j = 0; j < 8; j++) o[i][j] = (float4_t)(0.f);
    float lrow[2] = {0.f, 0.f};                          // q = qg*32 + qs*16 + nidx

    // K staging (conflict-free): thread -> key n_s = tid&15, chunk c_s = tid>>4
    const int c_s = tid >> 4, n_s = tid & 15;
    const int kfbase = (c_s >> 2) * 512 + ((c_s & 3) * 16 + n_s) * 8;
    auto loadKregs = [&](short8 (&kr)[4], int tt) {
        #pragma unroll
        for (int rr = 0; rr < 4; rr++)
            kr[rr] = *(const short8*)(Kg + (size_t)(k00 + tt * 64 + rr * 16 + n_s) * CC + c_s * 8);
    };
    auto stageK = [&](int buf, const short8 (&kr)[4]) {
        #pragma unroll
        for (int rr = 0; rr < 4; rr++) *(short8*)(&Kl[buf][rr * 4096 + kfbase]) = kr[rr];
    };
    auto loadVregs = [&](short8 (&vr)[4], int tt) {
        #pragma unroll
        for (int mg = 0; mg < 2; mg++)
            #pragma unroll
            for (int kst = 0; kst < 2; kst++)
                vr[mg * 2 + kst] = *(const short8*)(Vg + (size_t)(w * 32 + mg * 16 + nidx) * HW
                                                    + k00 + tt * 64 + kst * 32 + quad * 8);
    };

    const float SC = 0.0625f * 1.44269504088896f;        // /sqrt(256) * log2(e)
    // P-write cells (swapped QK): acc s[kgrp][qs] holds keys kgrp*16+quad*4+r
    // at q=nidx. Octet G = quad>>1; cell = (kgrp*2+G)*16 + (nidx ^ (G*4));
    // elem j0 = (quad&1)*4. XOR-4 swizzle spreads even/odd-quad banks.
    const int Gp = quad >> 1;
    const int pcell_lo = (nidx ^ (Gp * 4));              // low cell index part
    const int pj0 = (quad & 1) * 4;
    // P-read cell for consumer lane: octet = lane>>4, q = lane&15, same XOR
    const int prcell = ((lane >> 4) << 4) | ((lane & 15) ^ (((lane >> 4) & 1) * 4));

    float4_t s00, s01, s10, s11;                         // s[kgrp][qs]
    auto expPhase = [&](int buf) {
        {
            float e0 = exp2f(s00[0] * SC), e1 = exp2f(s00[1] * SC);
            float e2 = exp2f(s00[2] * SC), e3 = exp2f(s00[3] * SC);
            lrow[0] += (e0 + e1) + (e2 + e3);
            uint2 pk; pk.x = pk2(e0, e1); pk.y = pk2(e2, e3);
            *(uint2*)(&Pbuf[buf][(qg * 2 + 0) * 2 + kh][(0 * 2 + Gp) * 16 + pcell_lo][pj0]) = pk;
        }
        {
            float e0 = exp2f(s01[0] * SC), e1 = exp2f(s01[1] * SC);
            float e2 = exp2f(s01[2] * SC), e3 = exp2f(s01[3] * SC);
            lrow[1] += (e0 + e1) + (e2 + e3);
            uint2 pk; pk.x = pk2(e0, e1); pk.y = pk2(e2, e3);
            *(uint2*)(&Pbuf[buf][(qg * 2 + 1) * 2 + kh][(0 * 2 + Gp) * 16 + pcell_lo][pj0]) = pk;
        }
        {
            float e0 = exp2f(s10[0] * SC), e1 = exp2f(s10[1] * SC);
            float e2 = exp2f(s10[2] * SC), e3 = exp2f(s10[3] * SC);
            lrow[0] += (e0 + e1) + (e2 + e3);
            uint2 pk; pk.x = pk2(e0, e1); pk.y = pk2(e2, e3);
            *(uint2*)(&Pbuf[buf][(qg * 2 + 0) * 2 + kh][(1 * 2 + Gp) * 16 + pcell_lo][pj0]) = pk;
        }
        {
            float e0 = exp2f(s11[0] * SC), e1 = exp2f(s11[1] * SC);
            float e2 = exp2f(s11[2] * SC), e3 = exp2f(s11[3] * SC);
            lrow[1] += (e0 + e1) + (e2 + e3);
            uint2 pk; pk.x = pk2(e0, e1); pk.y = pk2(e2, e3);
            *(uint2*)(&Pbuf[buf][(qg * 2 + 1) * 2 + kh][(1 * 2 + Gp) * 16 + pcell_lo][pj0]) = pk;
        }
    };

    short8 kregs[4], vA[4], vB[4];

    // merged iteration t: PV(t)+QK(t+1) -> loads (r11/r13 placement) -> exp -> barrier
    auto ITER = [&](int t, const short8 (&vCur)[4], short8 (&vNext)[4]) {
        const int pb = t & 1;                            // P buffer for PV(t)
        const int kbuf = (t + 1) & 1;                    // Kl buffer for QK(t+1)
        s00 = (float4_t)(0.f); s01 = (float4_t)(0.f);
        s10 = (float4_t)(0.f); s11 = (float4_t)(0.f);
        #pragma unroll
        for (int i = 0; i < 8; i++) {
            short8 k0 = *(const short8*)(&Kl[kbuf][((kh * 2 + 0) * 8 + i) * 512 + lane * 8]);
            short8 k1 = *(const short8*)(&Kl[kbuf][((kh * 2 + 1) * 8 + i) * 512 + lane * 8]);
            // A = K (m=key), B = theta (n=q)
            s00 = __builtin_amdgcn_mfma_f32_16x16x32_bf16(k0, th[0][i], s00, 0, 0, 0);
            s01 = __builtin_amdgcn_mfma_f32_16x16x32_bf16(k0, th[1][i], s01, 0, 0, 0);
            s10 = __builtin_amdgcn_mfma_f32_16x16x32_bf16(k1, th[0][i], s10, 0, 0, 0);
            s11 = __builtin_amdgcn_mfma_f32_16x16x32_bf16(k1, th[1][i], s11, 0, 0, 0);
            short8 pf0 = *(const short8*)(&Pbuf[pb][i * 2 + 0][prcell][0]);
            short8 pf1 = *(const short8*)(&Pbuf[pb][i * 2 + 1][prcell][0]);
            o[0][i] = __builtin_amdgcn_mfma_f32_16x16x32_bf16(vCur[0], pf0, o[0][i], 0, 0, 0);
            o[0][i] = __builtin_amdgcn_mfma_f32_16x16x32_bf16(vCur[1], pf1, o[0][i], 0, 0, 0);
            o[1][i] = __builtin_amdgcn_mfma_f32_16x16x32_bf16(vCur[2], pf0, o[1][i], 0, 0, 0);
            o[1][i] = __builtin_amdgcn_mfma_f32_16x16x32_bf16(vCur[3], pf1, o[1][i], 0, 0, 0);
        }
        loadVregs(vNext, t + 1);                          // WAR-safe: PV(t) consumed vCur
        expPhase((t + 1) & 1);
        if (t < 30) {
            stageK((t + 2) & 1, kregs);                   // Kl[t&1] safe per barrier(t-1)
            loadKregs(kregs, (t + 3 < 32) ? t + 3 : 31);
        }
        __syncthreads();                                  // P(t+1) + Kl[t+2] ready
    };

    // ---- prologue ----
    loadKregs(kregs, 0); loadVregs(vA, 0);
    stageK(0, kregs);
    loadKregs(kregs, 1);
    __syncthreads();                                     // Kl[0] ready
    s00 = (float4_t)(0.f); s01 = (float4_t)(0.f); s10 = (float4_t)(0.f); s11 = (float4_t)(0.f);
    #pragma unroll
    for (int kb = 0; kb < 8; kb++) {
        short8 k0 = *(const short8*)(&Kl[0][((kh * 2 + 0) * 8 + kb) * 512 + lane * 8]);
        short8 k1 = *(const short8*)(&Kl[0][((kh * 2 + 1) * 8 + kb) * 512 + lane * 8]);
        s00 = __builtin_amdgcn_mfma_f32_16x16x32_bf16(k0, th[0][kb], s00, 0, 0, 0);
        s01 = __builtin_amdgcn_mfma_f32_16x16x32_bf16(k0, th[1][kb], s01, 0, 0, 0);
        s10 = __builtin_amdgcn_mfma_f32_16x16x32_bf16(k1, th[0][kb], s10, 0, 0, 0);
        s11 = __builtin_amdgcn_mfma_f32_16x16x32_bf16(k1, th[1][kb], s11, 0, 0, 0);
    }
    expPhase(0);
    stageK(1, kregs);                                    // Kl[1] = K(1)
    loadKregs(kregs, 2);
    __syncthreads();                                     // P(0) + Kl[1] ready

    // ---- main loop: 31 merged iters (even/odd static V buffers) ----
    #pragma unroll 1
    for (int tt = 0; tt < 15; tt++) {
        ITER(tt * 2, vA, vB);
        ITER(tt * 2 + 1, vB, vA);
    }
    ITER(30, vA, vB);
    // ---- final PV(31): Pbuf[1], vB = V(31) ----
    #pragma unroll
    for (int i = 0; i < 8; i++) {
        short8 pf0 = *(const short8*)(&Pbuf[1][i * 2 + 0][prcell][0]);
        short8 pf1 = *(const short8*)(&Pbuf[1][i * 2 + 1][prcell][0]);
        o[0][i] = __builtin_amdgcn_mfma_f32_16x16x32_bf16(vB[0], pf0, o[0][i], 0, 0, 0);
        o[0][i] = __builtin_amdgcn_mfma_f32_16x16x32_bf16(vB[1], pf1, o[0][i], 0, 0, 0);
        o[1][i] = __builtin_amdgcn_mfma_f32_16x16x32_bf16(vB[2], pf0, o[1][i], 0, 0, 0);
        o[1][i] = __builtin_amdgcn_mfma_f32_16x16x32_bf16(vB[3], pf1, o[1][i], 0, 0, 0);
    }

    // ---- epilogue: l (lane q=nidx; reduce over quads, then kh waves) ----
    #pragma unroll
    for (int qs = 0; qs < 2; qs++) {
        float v = lrow[qs];
        v += __shfl_xor(v, 16);
        v += __shfl_xor(v, 32);
        if (quad == 0) Lbuf[kh][qg * 32 + qs * 16 + nidx] = v;
    }
    __syncthreads();
    if (tid < 128)
        lw[(size_t)h * SEQ + seq0 + p0 + tid] = Lbuf[0][tid] + Lbuf[1][tid];
    ushort* Op = Ow + ((size_t)h * SEQ + seq0 + p0) * CC;
    #pragma unroll
    for (int mg = 0; mg < 2; mg++)
        #pragma unroll
        for (int qq = 0; qq < 8; qq++) {
            uint2 pk;
            pk.x = pk2(o[mg][qq][0], o[mg][qq][1]);
            pk.y = pk2(o[mg][qq][2], o[mg][qq][3]);
            *(uint2*)(Op + (size_t)(qq * 16 + nidx) * CC + w * 32 + mg * 16 + quad * 4) = pk;
        }
}

// ---- kernel 4: fused reduce+final with on-the-fly fp32->bf16 weight
// conversion. One block per (p-tile, n): combine the two key-half partials
// once into a swizzled LDS tile, then MFMA from LDS.
// out[n][co][p] = x + b[co] + sum_k W[co][k]*fT[p][k]
__global__ __launch_bounds__(512)
void k_final(const float* __restrict__ cw,
             const float* __restrict__ bc,
             const ushort* __restrict__ Ow,
             const float* __restrict__ lw,
             const float* __restrict__ x,
             float* __restrict__ out) {
    __shared__ __align__(16) ushort F[64][256];          // combined fT tile, XOR-swizzled
    const int n = blockIdx.z;
    const int p0 = blockIdx.x * 64;
    const int tid = threadIdx.x;

    // stage+combine: thread -> row r = tid>>3, chunks (tid&7)+8i (16B each)
    {
        const int r = tid >> 3;
        const int c0 = tid & 7;
        const size_t grow = (size_t)n * HW + p0 + r;
        const float li = 1.0f / (lw[grow] + lw[SEQ + grow]);
        const short8* O0 = (const short8*)(Ow + grow * CC);
        const short8* O1 = (const short8*)(Ow + SEQ * CC + grow * CC);
        #pragma unroll
        for (int i = 0; i < 4; i++) {
            int ch = c0 + 8 * i;
            short8 a = O0[ch];
            short8 b = O1[ch];
            union { short8 s; unsigned u[4]; } pk;
            float f[8];
            #pragma unroll
            for (int j = 0; j < 8; j++)
                f[j] = (b2f((ushort)a[j]) + b2f((ushort)b[j])) * li;
            pk.u[0] = pk2(f[0], f[1]); pk.u[1] = pk2(f[2], f[3]);
            pk.u[2] = pk2(f[4], f[5]); pk.u[3] = pk2(f[6], f[7]);
            int swz = ch ^ (r & 7);                      // bank-spread (G4)
            *(short8*)(&F[r][swz * 8]) = pk.s;
        }
    }
    __syncthreads();

    const int w = tid >> 6, lane = tid & 63;
    const int nidx = lane & 15, quad = lane >> 4;
    const int co_base = w * 32;
    float4_t acc[2][4];
    #pragma unroll
    for (int i = 0; i < 2; i++)
        #pragma unroll
        for (int j = 0; j < 4; j++) acc[i][j] = (float4_t)(0.f);

    const float* a0row = cw + (size_t)(co_base + nidx) * CC + quad * 8;
    const float* a1row = cw + (size_t)(co_base + 16 + nidx) * CC + quad * 8;
    for (int ks = 0; ks < 8; ks++) {
        float4_t w00 = *(const float4_t*)(a0row + ks * 32);
        float4_t w01 = *(const float4_t*)(a0row + ks * 32 + 4);
        float4_t w10 = *(const float4_t*)(a1row + ks * 32);
        float4_t w11 = *(const float4_t*)(a1row + ks * 32 + 4);
        union { short8 s; unsigned u[4]; } a0, a1;
        a0.u[0] = pk2(w00[0], w00[1]); a0.u[1] = pk2(w00[2], w00[3]);
        a0.u[2] = pk2(w01[0], w01[1]); a0.u[3] = pk2(w01[2], w01[3]);
        a1.u[0] = pk2(w10[0], w10[1]); a1.u[1] = pk2(w10[2], w10[3]);
        a1.u[2] = pk2(w11[0], w11[1]); a1.u[3] = pk2(w11[2], w11[3]);
        #pragma unroll
        for (int pb = 0; pb < 4; pb++) {
            int row = pb * 16 + nidx;
            int chunk = (ks * 4 + quad) ^ (row & 7);     // matches write swizzle
            short8 bb = *(const short8*)(&F[row][chunk * 8]);
            acc[0][pb] = __builtin_amdgcn_mfma_f32_16x16x32_bf16(a0.s, bb, acc[0][pb], 0, 0, 0);
            acc[1][pb] = __builtin_amdgcn_mfma_f32_16x16x32_bf16(a1.s, bb, acc[1][pb], 0, 0, 0);
        }
    }

    #pragma unroll
    for (int cb = 0; cb < 2; cb++) {
        #pragma unroll
        for (int pb = 0; pb < 4; pb++) {
            #pragma unroll
            for (int r2 = 0; r2 < 4; r2++) {
                int co = co_base + cb * 16 + quad * 4 + r2;
                size_t idx = ((size_t)n * CC + co) * HW + p0 + pb * 16 + nidx;
                out[idx] = x[idx] + bc[co] + acc[cb][pb][r2];
            }
        }
    }
}

extern "C" void kernel_launch(void* const* d_in, const int* in_sizes, int n_in,
                              void* d_out, int out_size, void* d_ws, size_t ws_size,
                              hipStream_t stream) {
    const float* x       = (const float*)d_in[0];
    const float* theta_w = (const float*)d_in[1];
    const float* theta_b = (const float*)d_in[2];
    const float* phi_w   = (const float*)d_in[3];
    const float* phi_b   = (const float*)d_in[4];
    const float* conv1_w = (const float*)d_in[5];
    const float* conv1_b = (const float*)d_in[6];
    float* out = (float*)d_out;

    unsigned short* gb  = (unsigned short*)d_ws;  // [N][256][4096] bf16 (V)
    unsigned short* thT = gb  + SEQ * CC;         // [SEQ][256] bf16
    unsigned short* phT = thT + SEQ * CC;         // [SEQ][256] bf16
    unsigned short* Ow  = phT + SEQ * CC;         // [2][SEQ][256] bf16 partial O
    float* lw = (float*)(Ow + 2 * SEQ * CC);      // [2][SEQ] fp32 partial l

    k_pp<<<dim3(64, 1, 4), 512, 0, stream>>>(x, theta_w, phi_w, theta_b, phi_b, gb, thT, phT);
    k_attn<<<dim3(256), 512, 0, stream>>>(thT, phT, gb, Ow, lw);
    k_final<<<dim3(64, 1, 4), 512, 0, stream>>>(conv1_w, conv1_b, Ow, lw, x, out);
}